// Round 1
// baseline (229.305 us; speedup 1.0000x reference)
//
#include <hip/hip_runtime.h>
#include <hip/hip_bf16.h>

#define N 2048
#define D 256

// ws layout (floats): fT [D][N] | sq [N] | rowsum [N]
// total = 524288 + 2048 + 2048 floats ~= 2.11 MB

__global__ void k_transpose(const float* __restrict__ feat, float* __restrict__ fT) {
    __shared__ float tile[64][65];
    const int bj = blockIdx.x & 31;   // 32 j-tiles
    const int bc = blockIdx.x >> 5;   // 4 c-tiles
    const int j0 = bj * 64, c0 = bc * 64;
    const int t = threadIdx.x;
    {
        const int cl = t & 63;
#pragma unroll
        for (int r = 0; r < 16; ++r) {
            const int jl = r * 4 + (t >> 6);
            const int j = j0 + jl;
            tile[jl][cl] = feat[(j & 1023) * 512 + (j >> 10) * 256 + c0 + cl];
        }
    }
    __syncthreads();
    {
        const int jl = t & 63;
#pragma unroll
        for (int r = 0; r < 16; ++r) {
            const int cl = r * 4 + (t >> 6);
            fT[(c0 + cl) * N + j0 + jl] = tile[jl][cl];
        }
    }
}

__global__ void k_sq(const float* __restrict__ feat, float* __restrict__ sq) {
    const int j = blockIdx.x;
    const int lane = threadIdx.x;  // 64
    const float4* row = (const float4*)(feat + (j & 1023) * 512 + (j >> 10) * 256);
    float4 v = row[lane];
    float s = v.x * v.x + v.y * v.y + v.z * v.z + v.w * v.w;
#pragma unroll
    for (int off = 32; off; off >>= 1) s += __shfl_down(s, off);
    if (lane == 0) sq[j] = s;
}

__global__ __launch_bounds__(256) void k_row(
    const float* __restrict__ feat, const float* __restrict__ labels,
    const float* __restrict__ fT, const float* __restrict__ sq,
    float* __restrict__ rowsum) {
    const int i = blockIdx.x;
    const int t = threadIdx.x;

    __shared__ float fi[D];
    __shared__ __align__(16) float ld2[N / 2];
    __shared__ __align__(16) float el2[N / 2];
    __shared__ float red[4];

    fi[t] = feat[(i & 1023) * 512 + (i >> 10) * 256 + t];
    __syncthreads();

    // ---- dot phase: thread t owns columns j = 4t+q (g=0) and 1024+4t+q (g=1)
    float a00 = 0.f, a01 = 0.f, a02 = 0.f, a03 = 0.f;
    float a10 = 0.f, a11 = 0.f, a12 = 0.f, a13 = 0.f;
    const float4* fT4 = (const float4*)fT;
#pragma unroll 4
    for (int c = 0; c < D; ++c) {
        const float fc = fi[c];
        const float4 v0 = fT4[c * (N / 4) + t];
        const float4 v1 = fT4[c * (N / 4) + t + 256];
        a00 = fmaf(fc, v0.x, a00); a01 = fmaf(fc, v0.y, a01);
        a02 = fmaf(fc, v0.z, a02); a03 = fmaf(fc, v0.w, a03);
        a10 = fmaf(fc, v1.x, a10); a11 = fmaf(fc, v1.y, a11);
        a12 = fmaf(fc, v1.z, a12); a13 = fmaf(fc, v1.w, a13);
    }

    const float sqi = sq[i];
    const float labi = labels[i & 1023];
    const float4 sq0 = ((const float4*)sq)[t];
    const float4 sq1 = ((const float4*)sq)[t + 256];
    const float4 lbv = ((const float4*)labels)[t];

    float ldq[4];
    ldq[0] = fabsf(labi - lbv.x);
    ldq[1] = fabsf(labi - lbv.y);
    ldq[2] = fabsf(labi - lbv.z);
    ldq[3] = fabsf(labi - lbv.w);

    float lg[2][4];
    lg[0][0] = -0.5f * sqrtf(fmaxf(sqi + sq0.x - 2.f * a00, 0.f));
    lg[0][1] = -0.5f * sqrtf(fmaxf(sqi + sq0.y - 2.f * a01, 0.f));
    lg[0][2] = -0.5f * sqrtf(fmaxf(sqi + sq0.z - 2.f * a02, 0.f));
    lg[0][3] = -0.5f * sqrtf(fmaxf(sqi + sq0.w - 2.f * a03, 0.f));
    lg[1][0] = -0.5f * sqrtf(fmaxf(sqi + sq1.x - 2.f * a10, 0.f));
    lg[1][1] = -0.5f * sqrtf(fmaxf(sqi + sq1.y - 2.f * a11, 0.f));
    lg[1][2] = -0.5f * sqrtf(fmaxf(sqi + sq1.z - 2.f * a12, 0.f));
    lg[1][3] = -0.5f * sqrtf(fmaxf(sqi + sq1.w - 2.f * a13, 0.f));

    // ---- row max (includes diagonal, like reference)
    float m = lg[0][0];
#pragma unroll
    for (int g = 0; g < 2; ++g)
#pragma unroll
        for (int q = 0; q < 4; ++q) m = fmaxf(m, lg[g][q]);
#pragma unroll
    for (int off = 32; off; off >>= 1) m = fmaxf(m, __shfl_xor(m, off));
    if ((t & 63) == 0) red[t >> 6] = m;
    __syncthreads();
    m = fmaxf(fmaxf(red[0], red[1]), fmaxf(red[2], red[3]));

    // ---- shifted logits, exp, pair-summed el
    float sh[2][4], e[2][4];
    float slg = 0.f;
#pragma unroll
    for (int g = 0; g < 2; ++g) {
#pragma unroll
        for (int q = 0; q < 4; ++q) {
            const int j = 4 * t + q + 1024 * g;
            sh[g][q] = lg[g][q] - m;
            const float ee = expf(sh[g][q]);
            e[g][q] = (j == i) ? 0.f : ee;
            if (j != i) slg += sh[g][q];
        }
    }
    ((float4*)ld2)[t] = make_float4(ldq[0], ldq[1], ldq[2], ldq[3]);
    ((float4*)el2)[t] = make_float4(e[0][0] + e[1][0], e[0][1] + e[1][1],
                                    e[0][2] + e[1][2], e[0][3] + e[1][3]);
    __syncthreads();

    // ---- denominators: dn[q] = sum_j [ld_j >= ldq[q]] * (el_j + el_{j+1024})
    float dn0 = 0.f, dn1 = 0.f, dn2 = 0.f, dn3 = 0.f;
#pragma unroll 4
    for (int j = 0; j < N / 2; ++j) {
        const float ldj = ld2[j];
        const float elj = el2[j];
        dn0 += (ldj >= ldq[0]) ? elj : 0.f;
        dn1 += (ldj >= ldq[1]) ? elj : 0.f;
        dn2 += (ldj >= ldq[2]) ? elj : 0.f;
        dn3 += (ldj >= ldq[3]) ? elj : 0.f;
    }
    const float dn[4] = {dn0, dn1, dn2, dn3};

    float contrib = slg;
#pragma unroll
    for (int q = 0; q < 4; ++q) {
        const float lq = logf(dn[q]);
#pragma unroll
        for (int g = 0; g < 2; ++g) {
            const int k = 4 * t + q + 1024 * g;
            if (k != i) contrib -= lq;
        }
    }

    // ---- block reduce sum
#pragma unroll
    for (int off = 32; off; off >>= 1) contrib += __shfl_xor(contrib, off);
    if ((t & 63) == 0) red[t >> 6] = contrib;
    __syncthreads();
    if (t == 0) rowsum[i] = red[0] + red[1] + red[2] + red[3];
}

__global__ void k_final(const float* __restrict__ rowsum, float* __restrict__ out) {
    __shared__ double rd[4];
    const int t = threadIdx.x;  // 256
    double s = 0.0;
#pragma unroll
    for (int r = 0; r < 8; ++r) s += (double)rowsum[t + 256 * r];
#pragma unroll
    for (int off = 32; off; off >>= 1) s += __shfl_down(s, off);
    if ((t & 63) == 0) rd[t >> 6] = s;
    __syncthreads();
    if (t == 0) {
        const double tot = rd[0] + rd[1] + rd[2] + rd[3];
        out[0] = (float)(-tot / ((double)N * (double)(N - 1)));
    }
}

extern "C" void kernel_launch(void* const* d_in, const int* in_sizes, int n_in,
                              void* d_out, int out_size, void* d_ws, size_t ws_size,
                              hipStream_t stream) {
    const float* feat = (const float*)d_in[0];
    const float* labels = (const float*)d_in[1];
    // d_in[2] (ranks) unused, matching reference
    float* ws = (float*)d_ws;
    float* fT = ws;
    float* sq = ws + (size_t)N * D;
    float* rowsum = sq + N;

    k_transpose<<<128, 256, 0, stream>>>(feat, fT);
    k_sq<<<N, 64, 0, stream>>>(feat, sq);
    k_row<<<N, 256, 0, stream>>>(feat, labels, fT, sq, rowsum);
    k_final<<<1, 256, 0, stream>>>(rowsum, (float*)d_out);
}

// Round 2
// 107.661 us; speedup vs baseline: 2.1299x; 2.1299x over previous
//
#include <hip/hip_runtime.h>
#include <hip/hip_bf16.h>

#define N 2048
#define D 256
#define NB 1024

// ws layout (floats): fT [D][N] | sq [N] | slab [NB] | rank [NB] (int) | blocksum [512]

__global__ void k_transpose(const float* __restrict__ feat, float* __restrict__ fT) {
    __shared__ float tile[64][65];
    const int bj = blockIdx.x & 31;   // 32 j-tiles
    const int bc = blockIdx.x >> 5;   // 4 c-tiles
    const int j0 = bj * 64, c0 = bc * 64;
    const int t = threadIdx.x;
    {
        const int cl = t & 63;
#pragma unroll
        for (int r = 0; r < 16; ++r) {
            const int jl = r * 4 + (t >> 6);
            const int j = j0 + jl;
            tile[jl][cl] = feat[(j & 1023) * 512 + (j >> 10) * 256 + c0 + cl];
        }
    }
    __syncthreads();
    {
        const int jl = t & 63;
#pragma unroll
        for (int r = 0; r < 16; ++r) {
            const int cl = r * 4 + (t >> 6);
            fT[(c0 + cl) * N + j0 + jl] = tile[jl][cl];
        }
    }
}

__global__ void k_sq(const float* __restrict__ feat, float* __restrict__ sq) {
    const int j = blockIdx.x;
    const int lane = threadIdx.x;  // 64
    const float4* row = (const float4*)(feat + (j & 1023) * 512 + (j >> 10) * 256);
    float4 v = row[lane];
    float s = v.x * v.x + v.y * v.y + v.z * v.z + v.w * v.w;
#pragma unroll
    for (int off = 32; off; off >>= 1) s += __shfl_down(s, off);
    if (lane == 0) sq[j] = s;
}

__global__ __launch_bounds__(1024) void k_sort(const float* __restrict__ labels,
                                               float* __restrict__ slab,
                                               int* __restrict__ rank) {
    __shared__ float key[NB];
    __shared__ int idx[NB];
    const int t = threadIdx.x;
    key[t] = labels[t];
    idx[t] = t;
    __syncthreads();
    for (int size = 2; size <= NB; size <<= 1) {
        for (int stride = size >> 1; stride > 0; stride >>= 1) {
            const int j = t ^ stride;
            if (j > t) {
                const bool up = ((t & size) == 0);
                const float ka = key[t], kb = key[j];
                const bool sw = up ? (ka > kb) : (ka < kb);
                if (sw) {
                    const int ia = idx[t], ib = idx[j];
                    key[t] = kb; key[j] = ka;
                    idx[t] = ib; idx[j] = ia;
                }
            }
            __syncthreads();
        }
    }
    slab[t] = key[t];
    rank[idx[t]] = t;
}

__global__ __launch_bounds__(512) void k_row(
    const float* __restrict__ feat, const float* __restrict__ labels,
    const float* __restrict__ fT, const float* __restrict__ sq,
    const float* __restrict__ slab, const int* __restrict__ rank,
    float* __restrict__ blocksum) {
    const int i0 = blockIdx.x * 4;
    const int t = threadIdx.x;
    const int lane = t & 63;
    const int wv = t >> 6;

    __shared__ __align__(16) float fiT[D][4];
    __shared__ __align__(16) float slb[NB];
    __shared__ __align__(16) float els[NB];
    __shared__ __align__(16) float E[NB + 4];
    __shared__ float red[8];
    __shared__ float wsum[8];

#pragma unroll
    for (int p = 0; p < 2; ++p) {
        const int flat = t + 512 * p;
        const int c = flat & 255;
        const int r = flat >> 8;
        const int i = i0 + r;
        fiT[c][r] = feat[(i & 1023) * 512 + (i >> 10) * 256 + c];
    }
    ((float2*)slb)[t] = ((const float2*)slab)[t];
    __syncthreads();

    // ---- dot phase: thread t owns cols {2t,2t+1} (g=0) and {1024+2t,1024+2t+1} (g=1)
    float acc[4][2][2];
#pragma unroll
    for (int r = 0; r < 4; ++r)
#pragma unroll
        for (int g = 0; g < 2; ++g)
#pragma unroll
            for (int q = 0; q < 2; ++q) acc[r][g][q] = 0.f;

    const float2* fT2 = (const float2*)fT;
#pragma unroll 2
    for (int c = 0; c < D; ++c) {
        const float2 b0 = fT2[c * (N / 2) + t];
        const float2 b1 = fT2[c * (N / 2) + 512 + t];
        const float4 a = *(const float4*)&fiT[c][0];
#define FMA_ROW(r, comp)                                  \
        acc[r][0][0] = fmaf(comp, b0.x, acc[r][0][0]);    \
        acc[r][0][1] = fmaf(comp, b0.y, acc[r][0][1]);    \
        acc[r][1][0] = fmaf(comp, b1.x, acc[r][1][0]);    \
        acc[r][1][1] = fmaf(comp, b1.y, acc[r][1][1]);
        FMA_ROW(0, a.x)
        FMA_ROW(1, a.y)
        FMA_ROW(2, a.z)
        FMA_ROW(3, a.w)
#undef FMA_ROW
    }

    const float2 lbv = ((const float2*)labels)[t];
    const float2 sqa = ((const float2*)sq)[t];
    const float2 sqb = ((const float2*)sq)[t + 512];
    const int2 rk = ((const int2*)rank)[t];

    float contrib = 0.f;

#pragma unroll
    for (int r = 0; r < 4; ++r) {
        const int i = i0 + r;
        const float sqi = sq[i];
        const float labi = labels[i & 1023];

        float lg[2][2];
        lg[0][0] = -0.5f * sqrtf(fmaxf(sqi + sqa.x - 2.f * acc[r][0][0], 0.f));
        lg[0][1] = -0.5f * sqrtf(fmaxf(sqi + sqa.y - 2.f * acc[r][0][1], 0.f));
        lg[1][0] = -0.5f * sqrtf(fmaxf(sqi + sqb.x - 2.f * acc[r][1][0], 0.f));
        lg[1][1] = -0.5f * sqrtf(fmaxf(sqi + sqb.y - 2.f * acc[r][1][1], 0.f));

        // ---- row max (includes diagonal, like reference; shift cancels exactly anyway)
        float m = fmaxf(fmaxf(lg[0][0], lg[0][1]), fmaxf(lg[1][0], lg[1][1]));
#pragma unroll
        for (int off = 32; off; off >>= 1) m = fmaxf(m, __shfl_xor(m, off));
        if (lane == 0) red[wv] = m;
        __syncthreads();
#pragma unroll
        for (int w = 0; w < 8; ++w) m = fmaxf(m, red[w]);

        // ---- shifted logits, exp, pair-summed el scattered into label-sorted order
        float e2[2];
#pragma unroll
        for (int q = 0; q < 2; ++q) {
            const int ja = 2 * t + q;
            const int jb = 1024 + 2 * t + q;
            const float sa = lg[0][q] - m;
            const float sb = lg[1][q] - m;
            const float ea = (ja == i) ? 0.f : expf(sa);
            const float eb = (jb == i) ? 0.f : expf(sb);
            if (ja != i) contrib += sa;
            if (jb != i) contrib += sb;
            e2[q] = ea + eb;
        }
        els[rk.x] = e2[0];
        els[rk.y] = e2[1];
        __syncthreads();

        // ---- block-parallel exclusive prefix sum of els -> E[0..NB]
        const float2 xv = ((const float2*)els)[t];
        const float s = xv.x + xv.y;
        float inc = s;
#pragma unroll
        for (int off = 1; off < 64; off <<= 1) {
            const float u = __shfl_up(inc, off);
            if (lane >= off) inc += u;
        }
        if (lane == 63) wsum[wv] = inc;
        __syncthreads();
        float woff = 0.f;
        for (int w = 0; w < wv; ++w) woff += wsum[w];
        const float base = woff + inc - s;
        ((float2*)E)[t] = make_float2(base, base + xv.x);
        if (t == 511) E[NB] = base + s;
        __syncthreads();
        const float total = E[NB];
        const int pc = rank[i & 1023];

        // ---- denominators via two binary searches on the V-shaped ld array
#pragma unroll
        for (int q = 0; q < 2; ++q) {
            const float tq = fabsf(labi - ((q == 0) ? lbv.x : lbv.y));
            float dn;
            if (tq > 0.f) {
                int ll = 0, lr = pc;  // first p in [0,pc] with ld < tq (guaranteed at pc)
                while (ll < lr) {
                    const int mid = (ll + lr) >> 1;
                    if (fabsf(labi - slb[mid]) < tq) lr = mid; else ll = mid + 1;
                }
                int hl = pc, hr = NB;  // first p in [pc,NB) with ld >= tq (sentinel NB)
                while (hl < hr) {
                    const int mid = (hl + hr) >> 1;
                    if (fabsf(labi - slb[mid]) >= tq) hr = mid; else hl = mid + 1;
                }
                dn = total - (E[hl] - E[ll]);
            } else {
                dn = total;  // ld_k == 0: nothing strictly smaller
            }
            const float lq = logf(dn);
            const int k0 = 2 * t + q, k1 = 1024 + 2 * t + q;
            contrib -= lq * (float)((k0 != i) + (k1 != i));
        }
        __syncthreads();  // protect els/E/red before next row reuses them
    }

    // ---- block reduce contrib
#pragma unroll
    for (int off = 32; off; off >>= 1) contrib += __shfl_xor(contrib, off);
    if (lane == 0) red[wv] = contrib;
    __syncthreads();
    if (t == 0) {
        float sb = 0.f;
#pragma unroll
        for (int w = 0; w < 8; ++w) sb += red[w];
        blocksum[blockIdx.x] = sb;
    }
}

__global__ void k_final(const float* __restrict__ bs, float* __restrict__ out) {
    __shared__ double rd[4];
    const int t = threadIdx.x;  // 256
    double s = (double)bs[t] + (double)bs[t + 256];
#pragma unroll
    for (int off = 32; off; off >>= 1) s += __shfl_down(s, off);
    if ((t & 63) == 0) rd[t >> 6] = s;
    __syncthreads();
    if (t == 0) {
        const double tot = rd[0] + rd[1] + rd[2] + rd[3];
        out[0] = (float)(-tot / ((double)N * (double)(N - 1)));
    }
}

extern "C" void kernel_launch(void* const* d_in, const int* in_sizes, int n_in,
                              void* d_out, int out_size, void* d_ws, size_t ws_size,
                              hipStream_t stream) {
    const float* feat = (const float*)d_in[0];
    const float* labels = (const float*)d_in[1];
    float* ws = (float*)d_ws;
    float* fT = ws;
    float* sq = ws + (size_t)N * D;
    float* slab = sq + N;
    int* rank = (int*)(slab + NB);
    float* bsum = (float*)(rank + NB);

    k_transpose<<<128, 256, 0, stream>>>(feat, fT);
    k_sq<<<N, 64, 0, stream>>>(feat, sq);
    k_sort<<<1, NB, 0, stream>>>(labels, slab, rank);
    k_row<<<512, 512, 0, stream>>>(feat, labels, fT, sq, slab, rank, bsum);
    k_final<<<1, 256, 0, stream>>>(bsum, (float*)d_out);
}

// Round 3
// 82.210 us; speedup vs baseline: 2.7892x; 1.3096x over previous
//
#include <hip/hip_runtime.h>
#include <hip/hip_bf16.h>

#define N 2048
#define NL 1024
#define D 256

using bfrag = __attribute__((ext_vector_type(8))) short;   // 8 bf16
using ffrag = __attribute__((ext_vector_type(4))) float;   // 4 f32 acc

// ws layout (bytes):
//   fB   [N*D] ushort  : [0, 1048576)
//   sq   [N]   f32     : +8192
//   slab [NL]  f32     : +4096
//   rank [NL]  i32     : +4096
//   sidx [NL]  i32     : +4096
//   bsum [256] f32     : +1024

__global__ void k_prep(const float* __restrict__ feat, ushort* __restrict__ fB,
                       float* __restrict__ sq) {
    const int j = blockIdx.x;   // 0..2047
    const int l = threadIdx.x;  // 64
    const float4 v = ((const float4*)(feat + (j & 1023) * 512 + (j >> 10) * 256))[l];
    float s = v.x * v.x + v.y * v.y + v.z * v.z + v.w * v.w;
#pragma unroll
    for (int off = 32; off; off >>= 1) s += __shfl_down(s, off);
    if (l == 0) sq[j] = s;
    ushort4 b;
    b.x = __builtin_bit_cast(unsigned short, __float2bfloat16(v.x));
    b.y = __builtin_bit_cast(unsigned short, __float2bfloat16(v.y));
    b.z = __builtin_bit_cast(unsigned short, __float2bfloat16(v.z));
    b.w = __builtin_bit_cast(unsigned short, __float2bfloat16(v.w));
    ((ushort4*)(fB + j * 256))[l] = b;
}

__global__ __launch_bounds__(1024) void k_sort(const float* __restrict__ labels,
                                               float* __restrict__ slab,
                                               int* __restrict__ rank,
                                               int* __restrict__ sidx) {
    __shared__ float key[NL];
    __shared__ int idx[NL];
    const int t = threadIdx.x;
    key[t] = labels[t];
    idx[t] = t;
    __syncthreads();
    for (int size = 2; size <= NL; size <<= 1) {
        for (int stride = size >> 1; stride > 0; stride >>= 1) {
            const int j = t ^ stride;
            if (j > t) {
                const bool up = ((t & size) == 0);
                const float ka = key[t], kb = key[j];
                const bool sw = up ? (ka > kb) : (ka < kb);
                if (sw) {
                    const int ia = idx[t], ib = idx[j];
                    key[t] = kb; key[j] = ka;
                    idx[t] = ib; idx[j] = ia;
                }
            }
            __syncthreads();
        }
    }
    slab[t] = key[t];
    sidx[t] = idx[t];
    rank[idx[t]] = t;
}

__global__ __launch_bounds__(1024) void k_main(
    const ushort* __restrict__ fB, const float* __restrict__ sq,
    const float* __restrict__ slab, const int* __restrict__ rank,
    const int* __restrict__ sidx, const float* __restrict__ labels,
    float* __restrict__ blocksum) {
    const int b = blockIdx.x;          // 256 blocks
    const int t = threadIdx.x;         // 1024
    const int l = t & 63, w = t >> 6;  // 16 waves
    const int tile0 = (b >> 1) * 16;   // MFMA A-tile row base (16 rows)
    const int half = b & 1;            // which 8 rows of the tile are ours
    const int i0 = b * 8;              // our global row base

    __shared__ __align__(16) float Eraw[8][NL];      // view-0 el, label-sorted
    __shared__ __align__(16) float Erw2[8][NL];      // view-1 el, label-sorted
    __shared__ __align__(16) float Epre[8][NL + 4];  // exclusive prefix + total
    __shared__ __align__(16) float slb[NL];
    __shared__ int sx[NL];
    __shared__ int rkl[NL];
    __shared__ float red[16];

    slb[t] = slab[t];
    sx[t] = sidx[t];
    rkl[t] = rank[t];

    // ---- MFMA gram: tile rows [tile0,tile0+16) x this wave's 128 cols
    const int colbase = w * 128;
    const int ko = (l >> 4) * 8;
    const ushort* arow = fB + (tile0 + (l & 15)) * D + ko;
    const ushort* brow = fB + (colbase + (l & 15)) * D + ko;
    ffrag acc[8];
#pragma unroll
    for (int n = 0; n < 8; ++n) acc[n] = (ffrag){0.f, 0.f, 0.f, 0.f};
#pragma unroll
    for (int kk = 0; kk < 8; ++kk) {
        const bfrag a = *(const bfrag*)(arow + kk * 32);
#pragma unroll
        for (int n = 0; n < 8; ++n) {
            const bfrag bb = *(const bfrag*)(brow + n * 16 * D + kk * 32);
            acc[n] = __builtin_amdgcn_mfma_f32_16x16x32_bf16(a, bb, acc[n], 0, 0, 0);
        }
    }

    __syncthreads();  // slb/sx/rkl ready

    // ---- epilogue: d2 -> lg -> e, scatter into label-sorted LDS rows
    float contrib = 0.f;
    const int rg = l >> 4;  // row-group 0..3 (4 rows each)
    if ((rg >> 1) == half) {
#pragma unroll
        for (int v = 0; v < 4; ++v) {
            const int gi = tile0 + rg * 4 + v;  // global row (ours)
            const int r = gi - i0;              // local row 0..7
            const float sqi = sq[gi];
#pragma unroll
            for (int n = 0; n < 8; ++n) {
                const int gj = colbase + n * 16 + (l & 15);
                const float d2 = sqi + sq[gj] - 2.f * acc[n][v];
                const float lg = -0.5f * sqrtf(fmaxf(d2, 0.f));
                const bool diag = (gj == gi);
                const float e = diag ? 0.f : expf(lg);
                if (!diag) contrib += lg;
                const int p = rkl[gj & 1023];
                if (gj < NL) Eraw[r][p] = e;
                else         Erw2[r][p] = e;
            }
        }
    }
    __syncthreads();

    // ---- per-row exclusive prefix sum of (Eraw + Erw2): wave (rw,h)
    const int rw = w >> 1, h = w & 1;
    {
        const float* s1 = &Eraw[rw][l * 16];
        const float* s2 = &Erw2[rw][l * 16];
        float pre[16];
        float run = 0.f;
#pragma unroll
        for (int c = 0; c < 4; ++c) {
            const float4 a = ((const float4*)s1)[c];
            const float4 bb = ((const float4*)s2)[c];
            pre[c * 4 + 0] = run; run += a.x + bb.x;
            pre[c * 4 + 1] = run; run += a.y + bb.y;
            pre[c * 4 + 2] = run; run += a.z + bb.z;
            pre[c * 4 + 3] = run; run += a.w + bb.w;
        }
        const float s = run;
        float inc = s;
#pragma unroll
        for (int off = 1; off < 64; off <<= 1) {
            const float u = __shfl_up(inc, off);
            if (l >= off) inc += u;
        }
        const float base = inc - s;
        if ((l >> 5) == h) {
            float* dst = &Epre[rw][l * 16];
#pragma unroll
            for (int c = 0; c < 4; ++c) {
                float4 o;
                o.x = base + pre[c * 4 + 0];
                o.y = base + pre[c * 4 + 1];
                o.z = base + pre[c * 4 + 2];
                o.w = base + pre[c * 4 + 3];
                ((float4*)dst)[c] = o;
            }
        }
        if (h == 1 && l == 63) Epre[rw][NL] = base + s;
    }
    __syncthreads();

    // ---- denominators via two binary searches on the V-shaped ld array
    {
        const int gi = i0 + rw;
        const float labi = labels[gi & 1023];
        const int pc = rkl[gi & 1023];
        const float total = Epre[rw][NL];
#pragma unroll
        for (int u = 0; u < 8; ++u) {
            const int p = h * 512 + u * 64 + l;
            const float tq = fabsf(labi - slb[p]);
            int ll = 0, lr = pc;  // first pos in [0,pc] with ld < tq (pc if tq==0)
            while (ll < lr) {
                const int mid = (ll + lr) >> 1;
                if (fabsf(labi - slb[mid]) < tq) lr = mid; else ll = mid + 1;
            }
            int hl = pc, hr = NL;  // first pos in [pc,NL) with ld >= tq (sentinel NL)
            while (hl < hr) {
                const int mid = (hl + hr) >> 1;
                if (fabsf(labi - slb[mid]) >= tq) hr = mid; else hl = mid + 1;
            }
            const float dn = total - (Epre[rw][hl] - Epre[rw][ll]);
            const float m2 = (sx[p] == (gi & 1023)) ? 1.f : 2.f;
            contrib -= m2 * logf(dn);
        }
    }

    // ---- block reduce
#pragma unroll
    for (int off = 32; off; off >>= 1) contrib += __shfl_xor(contrib, off);
    if (l == 0) red[w] = contrib;
    __syncthreads();
    if (t == 0) {
        float sb = 0.f;
#pragma unroll
        for (int q = 0; q < 16; ++q) sb += red[q];
        blocksum[b] = sb;
    }
}

__global__ void k_final(const float* __restrict__ bs, float* __restrict__ out) {
    __shared__ double rd[4];
    const int t = threadIdx.x;  // 256
    double s = (double)bs[t];
#pragma unroll
    for (int off = 32; off; off >>= 1) s += __shfl_down(s, off);
    if ((t & 63) == 0) rd[t >> 6] = s;
    __syncthreads();
    if (t == 0) {
        const double tot = rd[0] + rd[1] + rd[2] + rd[3];
        out[0] = (float)(-tot / ((double)N * (double)(N - 1)));
    }
}

extern "C" void kernel_launch(void* const* d_in, const int* in_sizes, int n_in,
                              void* d_out, int out_size, void* d_ws, size_t ws_size,
                              hipStream_t stream) {
    const float* feat = (const float*)d_in[0];
    const float* labels = (const float*)d_in[1];
    char* ws = (char*)d_ws;
    ushort* fB = (ushort*)ws;                       // 1048576 B
    float* sq = (float*)(ws + 1048576);             // 8192 B
    float* slab = (float*)(ws + 1048576 + 8192);    // 4096 B
    int* rank = (int*)(ws + 1048576 + 12288);       // 4096 B
    int* sidx = (int*)(ws + 1048576 + 16384);       // 4096 B
    float* bsum = (float*)(ws + 1048576 + 20480);   // 1024 B

    k_prep<<<N, 64, 0, stream>>>(feat, fB, sq);
    k_sort<<<1, NL, 0, stream>>>(labels, slab, rank, sidx);
    k_main<<<256, 1024, 0, stream>>>(fB, sq, slab, rank, sidx, labels, bsum);
    k_final<<<1, 256, 0, stream>>>(bsum, (float*)d_out);
}

// Round 4
// 73.725 us; speedup vs baseline: 3.1103x; 1.1151x over previous
//
#include <hip/hip_runtime.h>
#include <hip/hip_bf16.h>

#define N 2048
#define NL 1024
#define D 256

using bfrag = __attribute__((ext_vector_type(8))) short;   // 8 bf16
using ffrag = __attribute__((ext_vector_type(4))) float;   // 4 f32 acc

__device__ inline float bf2f(ushort u) {
    union { unsigned int i; float f; } x;
    x.i = ((unsigned int)u) << 16;
    return x.f;
}
__device__ inline ushort f2bf(float f) {
    return __builtin_bit_cast(unsigned short, __float2bfloat16(f));
}

// ================= NEW PATH (needs ~9.47 MB ws) =================
// ws layout (bytes):
//   fB   [N*D]   ushort : [0, 1048576)
//   eG   [N*N]   ushort : [1048576, 9437184)
//   sq   [N]     f32    : [9437184, 9445376)
//   slab [NL]    f32    : [9445376, 9449472)
//   rank [NL]    i32    : [9449472, 9453568)
//   sidx [NL]    i32    : [9453568, 9457664)
//   bsg  [256]   f32    : [9457664, 9458688)
//   bss  [2048]  f32    : [9458688, 9466880)

__global__ __launch_bounds__(512) void k_prep2(
    const float* __restrict__ feat, const float* __restrict__ labels,
    ushort* __restrict__ fB, float* __restrict__ sq,
    float* __restrict__ slab, int* __restrict__ rank, int* __restrict__ sidx) {
    __shared__ float lab[NL];
    const int t = threadIdx.x;
    const int b = blockIdx.x;
    if (b >= 256) {
        // ---- counting-rank sort of 1024 labels (2 blocks x 512 thr)
        lab[t] = labels[t];
        lab[t + 512] = labels[t + 512];
        __syncthreads();
        const int j = (b - 256) * 512 + t;
        const float lj = lab[j];
        int r = 0;
#pragma unroll 4
        for (int k = 0; k < NL; ++k) {
            const float lk = lab[k];
            r += (lk < lj) ? 1 : ((lk == lj && k < j) ? 1 : 0);
        }
        slab[r] = lj;
        sidx[r] = j;
        rank[j] = r;
        return;
    }
    // ---- prep: 8 rows per block, one row per wave
    const int l = t & 63;
    const int row = b * 8 + (t >> 6);
    const float4 v = ((const float4*)(feat + (row & 1023) * 512 + (row >> 10) * 256))[l];
    float s = v.x * v.x + v.y * v.y + v.z * v.z + v.w * v.w;
#pragma unroll
    for (int off = 32; off; off >>= 1) s += __shfl_down(s, off);
    if (l == 0) sq[row] = s;
    ushort4 o;
    o.x = f2bf(v.x); o.y = f2bf(v.y); o.z = f2bf(v.z); o.w = f2bf(v.w);
    ((ushort4*)(fB + row * D))[l] = o;
}

__global__ __launch_bounds__(512) void k_G(
    const ushort* __restrict__ fB, const float* __restrict__ sq,
    ushort* __restrict__ eG, float* __restrict__ bsg) {
    const int b = blockIdx.x;          // 256
    const int t = threadIdx.x;         // 512 = 8 waves
    const int l = t & 63, w = t >> 6;
    const int tile0 = (b >> 1) * 16;               // 16-row A tile
    const int colbase = (b & 1) * 1024 + w * 128;  // this wave's 128 cols
    __shared__ float red[8];

    const int ko = (l >> 4) * 8;
    const ushort* arow = fB + (tile0 + (l & 15)) * D + ko;
    const ushort* brow = fB + (colbase + (l & 15)) * D + ko;
    ffrag acc[8];
#pragma unroll
    for (int n = 0; n < 8; ++n) acc[n] = (ffrag){0.f, 0.f, 0.f, 0.f};
#pragma unroll
    for (int kk = 0; kk < 8; ++kk) {
        const bfrag a = *(const bfrag*)(arow + kk * 32);
#pragma unroll
        for (int n = 0; n < 8; ++n) {
            const bfrag bb = *(const bfrag*)(brow + n * 16 * D + kk * 32);
            acc[n] = __builtin_amdgcn_mfma_f32_16x16x32_bf16(a, bb, acc[n], 0, 0, 0);
        }
    }

    // epilogue: all 16 tile rows belong to this block's output
    const int rg = l >> 4;
    float lgsum = 0.f;
#pragma unroll
    for (int v = 0; v < 4; ++v) {
        const int gi = tile0 + rg * 4 + v;
        const float sqi = sq[gi];
#pragma unroll
        for (int n = 0; n < 8; ++n) {
            const int gj = colbase + n * 16 + (l & 15);
            const float d2 = sqi + sq[gj] - 2.f * acc[n][v];
            const float lg = -0.5f * sqrtf(fmaxf(d2, 0.f));
            const bool diag = (gj == gi);
            const float e = diag ? 0.f : expf(lg);
            if (!diag) lgsum += lg;
            eG[(size_t)gi * N + gj] = f2bf(e);
        }
    }

#pragma unroll
    for (int off = 32; off; off >>= 1) lgsum += __shfl_xor(lgsum, off);
    if (l == 0) red[w] = lgsum;
    __syncthreads();
    if (t == 0) {
        float sb = 0.f;
#pragma unroll
        for (int q = 0; q < 8; ++q) sb += red[q];
        bsg[b] = sb;
    }
}

__global__ __launch_bounds__(256) void k_S(
    const ushort* __restrict__ eG, const float* __restrict__ labels,
    const float* __restrict__ slab, const int* __restrict__ rank,
    const int* __restrict__ sidx, float* __restrict__ bss) {
    const int i = blockIdx.x;          // 2048 rows
    const int t = threadIdx.x;         // 256 = 4 waves
    const int l = t & 63, w = t >> 6;

    __shared__ __align__(16) ushort enat[N];   // 4 KB
    __shared__ __align__(16) float slb[NL];    // 4 KB
    __shared__ __align__(16) int sx[NL];       // 4 KB
    __shared__ __align__(16) float E[NL + 8];  // 4 KB
    __shared__ float wpart[4];
    __shared__ float red[4];

    ((uint4*)enat)[t] = ((const uint4*)(eG + (size_t)i * N))[t];
    ((float4*)slb)[t] = ((const float4*)slab)[t];
    ((int4*)sx)[t] = ((const int4*)sidx)[t];
    __syncthreads();

    // gather into sorted order (both views summed), thread owns p = 4t..4t+3
    float val[4], pre[4];
    {
        const int4 s4 = ((const int4*)sx)[t];
        val[0] = bf2f(enat[s4.x]) + bf2f(enat[s4.x + 1024]);
        val[1] = bf2f(enat[s4.y]) + bf2f(enat[s4.y + 1024]);
        val[2] = bf2f(enat[s4.z]) + bf2f(enat[s4.z + 1024]);
        val[3] = bf2f(enat[s4.w]) + bf2f(enat[s4.w + 1024]);
    }
    float run = 0.f;
#pragma unroll
    for (int q = 0; q < 4; ++q) { pre[q] = run; run += val[q]; }
    const float s = run;
    float inc = s;
#pragma unroll
    for (int off = 1; off < 64; off <<= 1) {
        const float u = __shfl_up(inc, off);
        if (l >= off) inc += u;
    }
    if (l == 63) wpart[w] = inc;
    __syncthreads();
    float woff = 0.f;
#pragma unroll
    for (int q = 0; q < 4; ++q) woff += (q < w) ? wpart[q] : 0.f;
    const float base = woff + inc - s;
    {
        float4 o;
        o.x = base + pre[0]; o.y = base + pre[1];
        o.z = base + pre[2]; o.w = base + pre[3];
        ((float4*)E)[t] = o;
    }
    if (t == 255) E[NL] = base + s;
    __syncthreads();

    const float total = E[NL];
    const float labi = labels[i & 1023];
    const int pc = rank[i & 1023];
    float contrib = 0.f;
#pragma unroll
    for (int u = 0; u < 4; ++u) {
        const int p = t + 256 * u;
        const float tq = fabsf(labi - slb[p]);
        int ll = 0, lr = pc;  // first pos in [0,pc] with ld < tq (pc if tq==0)
        while (ll < lr) {
            const int mid = (ll + lr) >> 1;
            if (fabsf(labi - slb[mid]) < tq) lr = mid; else ll = mid + 1;
        }
        int hl = pc, hr = NL;  // first pos in [pc,NL) with ld >= tq (sentinel NL)
        while (hl < hr) {
            const int mid = (hl + hr) >> 1;
            if (fabsf(labi - slb[mid]) >= tq) hr = mid; else hl = mid + 1;
        }
        const float dn = total - (E[hl] - E[ll]);
        const float m2 = (sx[p] == (i & 1023)) ? 1.f : 2.f;
        contrib -= m2 * logf(dn);
    }

#pragma unroll
    for (int off = 32; off; off >>= 1) contrib += __shfl_xor(contrib, off);
    if (l == 0) red[w] = contrib;
    __syncthreads();
    if (t == 0) bss[i] = red[0] + red[1] + red[2] + red[3];
}

__global__ void k_final2(const float* __restrict__ bsg, const float* __restrict__ bss,
                         float* __restrict__ out) {
    __shared__ double rd[4];
    const int t = threadIdx.x;  // 256
    double s = (double)bsg[t];
#pragma unroll
    for (int r = 0; r < 8; ++r) s += (double)bss[t + 256 * r];
#pragma unroll
    for (int off = 32; off; off >>= 1) s += __shfl_down(s, off);
    if ((t & 63) == 0) rd[t >> 6] = s;
    __syncthreads();
    if (t == 0) {
        const double tot = rd[0] + rd[1] + rd[2] + rd[3];
        out[0] = (float)(-tot / ((double)N * (double)(N - 1)));
    }
}

// ================= FALLBACK PATH (round-3, ~1.07 MB ws) =================

__global__ void k_prep(const float* __restrict__ feat, ushort* __restrict__ fB,
                       float* __restrict__ sq) {
    const int j = blockIdx.x;
    const int l = threadIdx.x;
    const float4 v = ((const float4*)(feat + (j & 1023) * 512 + (j >> 10) * 256))[l];
    float s = v.x * v.x + v.y * v.y + v.z * v.z + v.w * v.w;
#pragma unroll
    for (int off = 32; off; off >>= 1) s += __shfl_down(s, off);
    if (l == 0) sq[j] = s;
    ushort4 b;
    b.x = f2bf(v.x); b.y = f2bf(v.y); b.z = f2bf(v.z); b.w = f2bf(v.w);
    ((ushort4*)(fB + j * 256))[l] = b;
}

__global__ __launch_bounds__(1024) void k_sort(const float* __restrict__ labels,
                                               float* __restrict__ slab,
                                               int* __restrict__ rank,
                                               int* __restrict__ sidx) {
    __shared__ float key[NL];
    __shared__ int idx[NL];
    const int t = threadIdx.x;
    key[t] = labels[t];
    idx[t] = t;
    __syncthreads();
    for (int size = 2; size <= NL; size <<= 1) {
        for (int stride = size >> 1; stride > 0; stride >>= 1) {
            const int j = t ^ stride;
            if (j > t) {
                const bool up = ((t & size) == 0);
                const float ka = key[t], kb = key[j];
                const bool sw = up ? (ka > kb) : (ka < kb);
                if (sw) {
                    const int ia = idx[t], ib = idx[j];
                    key[t] = kb; key[j] = ka;
                    idx[t] = ib; idx[j] = ia;
                }
            }
            __syncthreads();
        }
    }
    slab[t] = key[t];
    sidx[t] = idx[t];
    rank[idx[t]] = t;
}

__global__ __launch_bounds__(1024) void k_main(
    const ushort* __restrict__ fB, const float* __restrict__ sq,
    const float* __restrict__ slab, const int* __restrict__ rank,
    const int* __restrict__ sidx, const float* __restrict__ labels,
    float* __restrict__ blocksum) {
    const int b = blockIdx.x;
    const int t = threadIdx.x;
    const int l = t & 63, w = t >> 6;
    const int tile0 = (b >> 1) * 16;
    const int half = b & 1;
    const int i0 = b * 8;

    __shared__ __align__(16) float Eraw[8][NL];
    __shared__ __align__(16) float Erw2[8][NL];
    __shared__ __align__(16) float Epre[8][NL + 4];
    __shared__ __align__(16) float slb[NL];
    __shared__ int sx[NL];
    __shared__ int rkl[NL];
    __shared__ float red[16];

    slb[t] = slab[t];
    sx[t] = sidx[t];
    rkl[t] = rank[t];

    const int colbase = w * 128;
    const int ko = (l >> 4) * 8;
    const ushort* arow = fB + (tile0 + (l & 15)) * D + ko;
    const ushort* brow = fB + (colbase + (l & 15)) * D + ko;
    ffrag acc[8];
#pragma unroll
    for (int n = 0; n < 8; ++n) acc[n] = (ffrag){0.f, 0.f, 0.f, 0.f};
#pragma unroll
    for (int kk = 0; kk < 8; ++kk) {
        const bfrag a = *(const bfrag*)(arow + kk * 32);
#pragma unroll
        for (int n = 0; n < 8; ++n) {
            const bfrag bb = *(const bfrag*)(brow + n * 16 * D + kk * 32);
            acc[n] = __builtin_amdgcn_mfma_f32_16x16x32_bf16(a, bb, acc[n], 0, 0, 0);
        }
    }
    __syncthreads();

    float contrib = 0.f;
    const int rg = l >> 4;
    if ((rg >> 1) == half) {
#pragma unroll
        for (int v = 0; v < 4; ++v) {
            const int gi = tile0 + rg * 4 + v;
            const int r = gi - i0;
            const float sqi = sq[gi];
#pragma unroll
            for (int n = 0; n < 8; ++n) {
                const int gj = colbase + n * 16 + (l & 15);
                const float d2 = sqi + sq[gj] - 2.f * acc[n][v];
                const float lg = -0.5f * sqrtf(fmaxf(d2, 0.f));
                const bool diag = (gj == gi);
                const float e = diag ? 0.f : expf(lg);
                if (!diag) contrib += lg;
                const int p = rkl[gj & 1023];
                if (gj < NL) Eraw[r][p] = e;
                else         Erw2[r][p] = e;
            }
        }
    }
    __syncthreads();

    const int rw = w >> 1, h = w & 1;
    {
        const float* s1 = &Eraw[rw][l * 16];
        const float* s2 = &Erw2[rw][l * 16];
        float pre[16];
        float run = 0.f;
#pragma unroll
        for (int c = 0; c < 4; ++c) {
            const float4 a = ((const float4*)s1)[c];
            const float4 bb = ((const float4*)s2)[c];
            pre[c * 4 + 0] = run; run += a.x + bb.x;
            pre[c * 4 + 1] = run; run += a.y + bb.y;
            pre[c * 4 + 2] = run; run += a.z + bb.z;
            pre[c * 4 + 3] = run; run += a.w + bb.w;
        }
        const float s = run;
        float inc = s;
#pragma unroll
        for (int off = 1; off < 64; off <<= 1) {
            const float u = __shfl_up(inc, off);
            if (l >= off) inc += u;
        }
        const float base = inc - s;
        if ((l >> 5) == h) {
            float* dst = &Epre[rw][l * 16];
#pragma unroll
            for (int c = 0; c < 4; ++c) {
                float4 o;
                o.x = base + pre[c * 4 + 0];
                o.y = base + pre[c * 4 + 1];
                o.z = base + pre[c * 4 + 2];
                o.w = base + pre[c * 4 + 3];
                ((float4*)dst)[c] = o;
            }
        }
        if (h == 1 && l == 63) Epre[rw][NL] = base + s;
    }
    __syncthreads();

    {
        const int gi = i0 + rw;
        const float labi = labels[gi & 1023];
        const int pc = rkl[gi & 1023];
        const float total = Epre[rw][NL];
#pragma unroll
        for (int u = 0; u < 8; ++u) {
            const int p = h * 512 + u * 64 + l;
            const float tq = fabsf(labi - slb[p]);
            int ll = 0, lr = pc;
            while (ll < lr) {
                const int mid = (ll + lr) >> 1;
                if (fabsf(labi - slb[mid]) < tq) lr = mid; else ll = mid + 1;
            }
            int hl = pc, hr = NL;
            while (hl < hr) {
                const int mid = (hl + hr) >> 1;
                if (fabsf(labi - slb[mid]) >= tq) hr = mid; else hl = mid + 1;
            }
            const float dn = total - (Epre[rw][hl] - Epre[rw][ll]);
            const float m2 = (sx[p] == (gi & 1023)) ? 1.f : 2.f;
            contrib -= m2 * logf(dn);
        }
    }

#pragma unroll
    for (int off = 32; off; off >>= 1) contrib += __shfl_xor(contrib, off);
    if (l == 0) red[w] = contrib;
    __syncthreads();
    if (t == 0) {
        float sb = 0.f;
#pragma unroll
        for (int q = 0; q < 16; ++q) sb += red[q];
        blocksum[b] = sb;
    }
}

__global__ void k_final(const float* __restrict__ bs, float* __restrict__ out) {
    __shared__ double rd[4];
    const int t = threadIdx.x;
    double s = (double)bs[t];
#pragma unroll
    for (int off = 32; off; off >>= 1) s += __shfl_down(s, off);
    if ((t & 63) == 0) rd[t >> 6] = s;
    __syncthreads();
    if (t == 0) {
        const double tot = rd[0] + rd[1] + rd[2] + rd[3];
        out[0] = (float)(-tot / ((double)N * (double)(N - 1)));
    }
}

extern "C" void kernel_launch(void* const* d_in, const int* in_sizes, int n_in,
                              void* d_out, int out_size, void* d_ws, size_t ws_size,
                              hipStream_t stream) {
    const float* feat = (const float*)d_in[0];
    const float* labels = (const float*)d_in[1];
    char* ws = (char*)d_ws;

    if (ws_size >= 9466880ULL) {
        ushort* fB = (ushort*)ws;
        ushort* eG = (ushort*)(ws + 1048576);
        float* sq = (float*)(ws + 9437184);
        float* slab = (float*)(ws + 9445376);
        int* rank = (int*)(ws + 9449472);
        int* sidx = (int*)(ws + 9453568);
        float* bsg = (float*)(ws + 9457664);
        float* bss = (float*)(ws + 9458688);

        k_prep2<<<258, 512, 0, stream>>>(feat, labels, fB, sq, slab, rank, sidx);
        k_G<<<256, 512, 0, stream>>>(fB, sq, eG, bsg);
        k_S<<<2048, 256, 0, stream>>>(eG, labels, slab, rank, sidx, bss);
        k_final2<<<1, 256, 0, stream>>>(bsg, bss, (float*)d_out);
    } else {
        ushort* fB = (ushort*)ws;
        float* sq = (float*)(ws + 1048576);
        float* slab = (float*)(ws + 1048576 + 8192);
        int* rank = (int*)(ws + 1048576 + 12288);
        int* sidx = (int*)(ws + 1048576 + 16384);
        float* bsum = (float*)(ws + 1048576 + 20480);

        k_prep<<<N, 64, 0, stream>>>(feat, fB, sq);
        k_sort<<<1, NL, 0, stream>>>(labels, slab, rank, sidx);
        k_main<<<256, 1024, 0, stream>>>(fB, sq, slab, rank, sidx, labels, bsum);
        k_final<<<1, 256, 0, stream>>>(bsum, (float*)d_out);
    }
}